// Round 6
// baseline (532.855 us; speedup 1.0000x reference)
//
#include <hip/hip_runtime.h>
#include <math.h>

// Siddon forward projection, 128^3 grid over [-1,1]^3, voxel = 1/64.
// K=16 lanes per LOR (alpha chunks), incremental traversal, depth-3 pipeline.
// NEW: rays are counting-sorted by crossing count (descending) so the 4 rays
// sharing a wave have near-equal trip counts (intra-wave balance).

static constexpr float VOX = 0.015625f;   // 2/128, exact power of two
static constexpr float INV_VOX = 64.0f;
static constexpr int   K = 16;
static constexpr int   LOGK = 4;
static constexpr int   NBINS = 512;

struct TState {
  float alx, aly, alz;   // next-crossing alpha per axis
  float dax, day, daz;   // alpha increment per crossing
  float acur, aend;
  int   ix, iy, iz;      // current voxel
  int   stx, sty, stz;   // walk direction
};

__device__ __forceinline__ void step4(const float* __restrict__ image,
                                      TState& S, float dif4[4], float v4[4]) {
#pragma unroll
  for (int j = 0; j < 4; ++j) {
    float anext = fminf(fminf(S.alx, S.aly), S.alz);
    float astop = fminf(anext, S.aend);
    float diff  = astop - S.acur;
    unsigned orv = (unsigned)(S.ix | S.iy | S.iz);
    bool  use   = (diff > 0.0f) & (orv < 128u);
    int   idx   = (S.ix << 14) | (S.iy << 7) | S.iz;
    v4[j]  = image[use ? idx : 0];
    dif4[j] = use ? diff : 0.0f;
    S.acur = astop;
    bool cx = S.alx <= anext;
    bool cy = S.aly <= anext;
    bool cz = S.alz <= anext;
    S.ix += cx ? S.stx : 0;  S.alx += cx ? S.dax : 0.0f;
    S.iy += cy ? S.sty : 0;  S.aly += cy ? S.day : 0.0f;
    S.iz += cz ? S.stz : 0;  S.alz += cz ? S.daz : 0.0f;
  }
}

// First plane index strictly past astart in walk order, its alpha, the alpha
// increment, the voxel containing astart, and crossing count in (astart,aend].
__device__ __forceinline__ void axis_init(float astart, float aend, float p0,
                                          float ds, float inv,
                                          int& st, int& iv, float& al, float& da,
                                          int& cnt) {
  float ts = (fmaf(astart, ds, p0) + 1.0f) * INV_VOX;
  float te = (fmaf(aend,   ds, p0) + 1.0f) * INV_VOX;
  int ip;
  if (ds > 0.0f) {
    ip = (int)floorf(ts) + 1;
    int il = (int)floorf(te); if (il > 128) il = 128;
    cnt = il - ip + 1; st = 1; iv = ip - 1;
  } else {
    ip = (int)ceilf(ts) - 1;
    int il = (int)ceilf(te); if (il < 0) il = 0;
    cnt = ip - il + 1; st = -1; iv = ip;
  }
  if (cnt < 0) cnt = 0;
  al = (fmaf((float)ip, VOX, -1.0f) - p0) * inv;
  da = VOX * fabsf(inv);
}

__device__ __forceinline__ void ray_setup(const float* L,
    float& p0x, float& p0y, float& p0z,
    float& dx, float& dy, float& dz,
    float& dsx, float& dsy, float& dsz,
    float& invx, float& invy, float& invz,
    float& amin, float& amax) {
  p0x = L[0]; p0y = L[1]; p0z = L[2];
  dx = L[3] - p0x; dy = L[4] - p0y; dz = L[5] - p0z;
  const float eps = 1e-9f;
  dsx = (fabsf(dx) < eps) ? eps : dx;
  dsy = (fabsf(dy) < eps) ? eps : dy;
  dsz = (fabsf(dz) < eps) ? eps : dz;
  invx = __builtin_amdgcn_rcpf(dsx);
  invy = __builtin_amdgcn_rcpf(dsy);
  invz = __builtin_amdgcn_rcpf(dsz);
  float a0 = (-1.0f - p0x) * invx, a1 = (1.0f - p0x) * invx;
  float axmin = fminf(a0, a1), axmax = fmaxf(a0, a1);
  a0 = (-1.0f - p0y) * invy; a1 = (1.0f - p0y) * invy;
  float aymin = fminf(a0, a1), aymax = fmaxf(a0, a1);
  a0 = (-1.0f - p0z) * invz; a1 = (1.0f - p0z) * invz;
  float azmin = fminf(a0, a1), azmax = fmaxf(a0, a1);
  amin = fmaxf(fmaxf(axmin, aymin), fmaxf(azmin, 0.0f));
  amax = fminf(fminf(axmax, aymax), fminf(azmax, 1.0f));
}

// --- sort pass 1: per-ray key (total crossing count) + histogram ------------
__global__ __launch_bounds__(256) void ray_keys(
    const float* __restrict__ lors, int n,
    int* __restrict__ keys, int* __restrict__ hist)
{
  int i = blockIdx.x * blockDim.x + threadIdx.x;
  if (i >= n) return;
  float p0x,p0y,p0z,dx,dy,dz,dsx,dsy,dsz,invx,invy,invz,amin,amax;
  ray_setup(lors + (long)i * 6, p0x,p0y,p0z, dx,dy,dz,
            dsx,dsy,dsz, invx,invy,invz, amin,amax);
  int key = 0;
  if (amax > amin) {
    int st, iv, c0, c1, c2; float al, da;
    axis_init(amin, amax, p0x, dsx, invx, st, iv, al, da, c0);
    axis_init(amin, amax, p0y, dsy, invy, st, iv, al, da, c1);
    axis_init(amin, amax, p0z, dsz, invz, st, iv, al, da, c2);
    int ns = c0 + c1 + c2;
    key = ns < 0 ? 0 : (ns > NBINS - 1 ? NBINS - 1 : ns);
  }
  keys[i] = key;
  atomicAdd(&hist[key], 1);
}

// --- sort pass 2: descending exclusive scan of 512 bins (one wave) ----------
__global__ __launch_bounds__(64) void scan_bins(
    const int* __restrict__ hist, int* __restrict__ offs)
{
  int lane = threadIdx.x;           // 64 lanes x 8 bins
  int base = lane * 8;
  int h[8]; int s = 0;
#pragma unroll
  for (int j = 0; j < 8; ++j) { h[j] = hist[base + j]; s += h[j]; }
  int t = s;                        // inclusive suffix-sum over lanes
#pragma unroll
  for (int d = 1; d < 64; d <<= 1) {
    int v = __shfl_down(t, d);
    if (lane + d < 64) t += v;
  }
  int excl = t - s;                 // sum over lanes > lane
  int run = 0;
#pragma unroll
  for (int j = 7; j >= 0; --j) { offs[base + j] = excl + run; run += h[j]; }
}

// --- sort pass 3: scatter permutation (descending key order) ----------------
__global__ __launch_bounds__(256) void scatter_perm(
    const int* __restrict__ keys, int* __restrict__ offs,
    int* __restrict__ perm, int n)
{
  int i = blockIdx.x * blockDim.x + threadIdx.x;
  if (i >= n) return;
  int pos = atomicAdd(&offs[keys[i]], 1);
  perm[pos] = i;
}

// --- traversal ---------------------------------------------------------------
__global__ __launch_bounds__(256) void siddon_fp(
    const float* __restrict__ image,
    const float* __restrict__ lors,
    float* __restrict__ out,
    const int* __restrict__ perm, int n)
{
  int t    = blockIdx.x * blockDim.x + threadIdx.x;
  int slot = t >> LOGK;
  int k    = t & (K - 1);
  if (slot >= n) return;
  int ray  = perm ? perm[slot] : slot;

  float p0x,p0y,p0z,dx,dy,dz,dsx,dsy,dsz,invx,invy,invz,amin,amax;
  ray_setup(lors + (long)ray * 6, p0x,p0y,p0z, dx,dy,dz,
            dsx,dsy,dsz, invx,invy,invz, amin,amax);

  float acc0 = 0.0f, acc1 = 0.0f;
  if (amax > amin) {
    float s      = (amax - amin) * (1.0f / (float)K);
    float astart = fmaf((float)k, s, amin);
    float aend   = (k == K - 1) ? amax : fmaf((float)(k + 1), s, amin);

    TState S;
    S.acur = astart; S.aend = aend;
    int cx, cy, cz;
    axis_init(astart, aend, p0x, dsx, invx, S.stx, S.ix, S.alx, S.dax, cx);
    axis_init(astart, aend, p0y, dsy, invy, S.sty, S.iy, S.aly, S.day, cy);
    axis_init(astart, aend, p0z, dsz, invz, S.stz, S.iz, S.alz, S.daz, cz);

    int ns = cx + cy + cz + 3;          // +1 final partial, +2 cushion
    int nb = (ns + 3) >> 2;             // batches of 4
    if (nb < 2) nb = 2;                 // prologue needs two batches

    float difA[4], difB[4], difC[4];
    float vA[4], vB[4], vC[4];

#define ISSUE(X)   step4(image, S, dif##X, v##X)
#define CONSUME(X)                                                  \
    do { acc0 = fmaf(dif##X[0], v##X[0], acc0);                     \
         acc1 = fmaf(dif##X[1], v##X[1], acc1);                     \
         acc0 = fmaf(dif##X[2], v##X[2], acc0);                     \
         acc1 = fmaf(dif##X[3], v##X[3], acc1); } while (0)

    ISSUE(A);
    ISSUE(B);
    int produce = nb - 2;
    while (produce >= 3) {
      ISSUE(C); CONSUME(A);
      ISSUE(A); CONSUME(B);
      ISSUE(B); CONSUME(C);
      produce -= 3;
    }
    if (produce == 2) {
      ISSUE(C); CONSUME(A);
      ISSUE(A); CONSUME(B);
      CONSUME(C); CONSUME(A);
    } else if (produce == 1) {
      ISSUE(C); CONSUME(A);
      CONSUME(B); CONSUME(C);
    } else {
      CONSUME(A); CONSUME(B);
    }
#undef ISSUE
#undef CONSUME

    float rlen = sqrtf(dx * dx + dy * dy + dz * dz);
    acc0 = (acc0 + acc1) * rlen;
    acc1 = 0.0f;
  }

  float acc = acc0 + acc1;
  acc += __shfl_xor(acc, 1);
  acc += __shfl_xor(acc, 2);
  acc += __shfl_xor(acc, 4);
  acc += __shfl_xor(acc, 8);
  if (k == 0) out[ray] = acc;
}

extern "C" void kernel_launch(void* const* d_in, const int* in_sizes, int n_in,
                              void* d_out, int out_size, void* d_ws, size_t ws_size,
                              hipStream_t stream) {
  const float* image = (const float*)d_in[0];   // [128,128,128] f32
  const float* lors  = (const float*)d_in[1];   // [N,6] f32
  float* out = (float*)d_out;                   // [N] f32
  int n = out_size;

  // ws layout: hist[512] | offs[512] | keys[n] | perm[n]
  size_t need = ((size_t)2 * NBINS + 2 * (size_t)n) * sizeof(int);
  int* perm = nullptr;
  if (ws_size >= need) {
    int* hist = (int*)d_ws;
    int* offs = hist + NBINS;
    int* keys = offs + NBINS;
    perm      = keys + n;
    hipMemsetAsync(hist, 0, NBINS * sizeof(int), stream);
    int blocks = (n + 255) / 256;
    hipLaunchKernelGGL(ray_keys,     dim3(blocks), dim3(256), 0, stream, lors, n, keys, hist);
    hipLaunchKernelGGL(scan_bins,    dim3(1),      dim3(64),  0, stream, hist, offs);
    hipLaunchKernelGGL(scatter_perm, dim3(blocks), dim3(256), 0, stream, keys, offs, perm, n);
  }

  long total = (long)n * K;
  int block = 256;
  int grid = (int)((total + block - 1) / block);
  hipLaunchKernelGGL(siddon_fp, dim3(grid), dim3(block), 0, stream,
                     image, lors, out, perm, n);
}

// Round 7
// 308.660 us; speedup vs baseline: 1.7264x; 1.7264x over previous
//
#include <hip/hip_runtime.h>
#include <math.h>

// Siddon forward projection, 128^3 grid over [-1,1]^3, voxel = 1/64.
// K=16 lanes per LOR (alpha chunks), incremental traversal, depth-3 pipeline.
// Rays counting-sorted by crossing count (descending) for intra-wave balance.
// Sort atomics are wave-ballot-aggregated (one atomic per wave per unique key)
// to kill hot-bin serialization (key=0 = rays missing the cube).

static constexpr float VOX = 0.015625f;   // 2/128, exact power of two
static constexpr float INV_VOX = 64.0f;
static constexpr int   K = 16;
static constexpr int   LOGK = 4;
static constexpr int   NBINS = 512;

struct TState {
  float alx, aly, alz;   // next-crossing alpha per axis
  float dax, day, daz;   // alpha increment per crossing
  float acur, aend;
  int   ix, iy, iz;      // current voxel
  int   stx, sty, stz;   // walk direction
};

__device__ __forceinline__ void step4(const float* __restrict__ image,
                                      TState& S, float dif4[4], float v4[4]) {
#pragma unroll
  for (int j = 0; j < 4; ++j) {
    float anext = fminf(fminf(S.alx, S.aly), S.alz);
    float astop = fminf(anext, S.aend);
    float diff  = astop - S.acur;
    unsigned orv = (unsigned)(S.ix | S.iy | S.iz);
    bool  use   = (diff > 0.0f) & (orv < 128u);
    int   idx   = (S.ix << 14) | (S.iy << 7) | S.iz;
    v4[j]  = image[use ? idx : 0];
    dif4[j] = use ? diff : 0.0f;
    S.acur = astop;
    bool cx = S.alx <= anext;
    bool cy = S.aly <= anext;
    bool cz = S.alz <= anext;
    S.ix += cx ? S.stx : 0;  S.alx += cx ? S.dax : 0.0f;
    S.iy += cy ? S.sty : 0;  S.aly += cy ? S.day : 0.0f;
    S.iz += cz ? S.stz : 0;  S.alz += cz ? S.daz : 0.0f;
  }
}

__device__ __forceinline__ void axis_init(float astart, float aend, float p0,
                                          float ds, float inv,
                                          int& st, int& iv, float& al, float& da,
                                          int& cnt) {
  float ts = (fmaf(astart, ds, p0) + 1.0f) * INV_VOX;
  float te = (fmaf(aend,   ds, p0) + 1.0f) * INV_VOX;
  int ip;
  if (ds > 0.0f) {
    ip = (int)floorf(ts) + 1;
    int il = (int)floorf(te); if (il > 128) il = 128;
    cnt = il - ip + 1; st = 1; iv = ip - 1;
  } else {
    ip = (int)ceilf(ts) - 1;
    int il = (int)ceilf(te); if (il < 0) il = 0;
    cnt = ip - il + 1; st = -1; iv = ip;
  }
  if (cnt < 0) cnt = 0;
  al = (fmaf((float)ip, VOX, -1.0f) - p0) * inv;
  da = VOX * fabsf(inv);
}

__device__ __forceinline__ void ray_setup(const float* L,
    float& p0x, float& p0y, float& p0z,
    float& dx, float& dy, float& dz,
    float& dsx, float& dsy, float& dsz,
    float& invx, float& invy, float& invz,
    float& amin, float& amax) {
  p0x = L[0]; p0y = L[1]; p0z = L[2];
  dx = L[3] - p0x; dy = L[4] - p0y; dz = L[5] - p0z;
  const float eps = 1e-9f;
  dsx = (fabsf(dx) < eps) ? eps : dx;
  dsy = (fabsf(dy) < eps) ? eps : dy;
  dsz = (fabsf(dz) < eps) ? eps : dz;
  invx = __builtin_amdgcn_rcpf(dsx);
  invy = __builtin_amdgcn_rcpf(dsy);
  invz = __builtin_amdgcn_rcpf(dsz);
  float a0 = (-1.0f - p0x) * invx, a1 = (1.0f - p0x) * invx;
  float axmin = fminf(a0, a1), axmax = fmaxf(a0, a1);
  a0 = (-1.0f - p0y) * invy; a1 = (1.0f - p0y) * invy;
  float aymin = fminf(a0, a1), aymax = fmaxf(a0, a1);
  a0 = (-1.0f - p0z) * invz; a1 = (1.0f - p0z) * invz;
  float azmin = fminf(a0, a1), azmax = fmaxf(a0, a1);
  amin = fmaxf(fmaxf(axmin, aymin), fmaxf(azmin, 0.0f));
  amax = fminf(fminf(axmax, aymax), fminf(azmax, 1.0f));
}

// --- sort pass 1: per-ray key + wave-aggregated histogram -------------------
__global__ __launch_bounds__(256) void ray_keys(
    const float* __restrict__ lors, int n,
    int* __restrict__ keys, int* __restrict__ hist)
{
  int i = blockIdx.x * blockDim.x + threadIdx.x;
  if (i >= n) return;
  float p0x,p0y,p0z,dx,dy,dz,dsx,dsy,dsz,invx,invy,invz,amin,amax;
  ray_setup(lors + (long)i * 6, p0x,p0y,p0z, dx,dy,dz,
            dsx,dsy,dsz, invx,invy,invz, amin,amax);
  int key = 0;
  if (amax > amin) {
    int st, iv, c0, c1, c2; float al, da;
    axis_init(amin, amax, p0x, dsx, invx, st, iv, al, da, c0);
    axis_init(amin, amax, p0y, dsy, invy, st, iv, al, da, c1);
    axis_init(amin, amax, p0z, dsz, invz, st, iv, al, da, c2);
    int ns = c0 + c1 + c2;
    key = ns < 0 ? 0 : (ns > NBINS - 1 ? NBINS - 1 : ns);
  }
  keys[i] = key;

  // one atomic per (wave, unique key)
  int lane = threadIdx.x & 63;
  unsigned long long active = __ballot(1);
  while (active) {
    int leader = __ffsll((long long)active) - 1;
    int lkey = __shfl(key, leader);
    unsigned long long same = __ballot(key == lkey);
    if (lane == leader) atomicAdd(&hist[lkey], (int)__popcll(same));
    active &= ~same;
  }
}

// --- sort pass 2: descending exclusive scan of 512 bins (one wave) ----------
__global__ __launch_bounds__(64) void scan_bins(
    const int* __restrict__ hist, int* __restrict__ offs)
{
  int lane = threadIdx.x;           // 64 lanes x 8 bins
  int base = lane * 8;
  int h[8]; int s = 0;
#pragma unroll
  for (int j = 0; j < 8; ++j) { h[j] = hist[base + j]; s += h[j]; }
  int t = s;                        // inclusive suffix-sum over lanes
#pragma unroll
  for (int d = 1; d < 64; d <<= 1) {
    int v = __shfl_down(t, d);
    if (lane + d < 64) t += v;
  }
  int excl = t - s;                 // sum over lanes > lane
  int run = 0;
#pragma unroll
  for (int j = 7; j >= 0; --j) { offs[base + j] = excl + run; run += h[j]; }
}

// --- sort pass 3: scatter via wave-aggregated returning atomics -------------
__global__ __launch_bounds__(256) void scatter_perm(
    const int* __restrict__ keys, int* __restrict__ offs,
    int* __restrict__ perm, int n)
{
  int i = blockIdx.x * blockDim.x + threadIdx.x;
  if (i >= n) return;
  int key = keys[i];
  int lane = threadIdx.x & 63;
  unsigned long long lt = ((unsigned long long)1 << lane) - 1ull;
  unsigned long long active = __ballot(1);
  int pos = 0;
  while (active) {
    int leader = __ffsll((long long)active) - 1;
    int lkey = __shfl(key, leader);
    unsigned long long same = __ballot(key == lkey);
    int base = 0;
    if (lane == leader) base = atomicAdd(&offs[lkey], (int)__popcll(same));
    base = __shfl(base, leader);
    if (key == lkey) pos = base + (int)__popcll(same & lt);
    active &= ~same;
  }
  perm[pos] = i;
}

// --- traversal ---------------------------------------------------------------
__global__ __launch_bounds__(256) void siddon_fp(
    const float* __restrict__ image,
    const float* __restrict__ lors,
    float* __restrict__ out,
    const int* __restrict__ perm, int n)
{
  int t    = blockIdx.x * blockDim.x + threadIdx.x;
  int slot = t >> LOGK;
  int k    = t & (K - 1);
  if (slot >= n) return;
  int ray  = perm ? perm[slot] : slot;

  float p0x,p0y,p0z,dx,dy,dz,dsx,dsy,dsz,invx,invy,invz,amin,amax;
  ray_setup(lors + (long)ray * 6, p0x,p0y,p0z, dx,dy,dz,
            dsx,dsy,dsz, invx,invy,invz, amin,amax);

  float acc0 = 0.0f, acc1 = 0.0f;
  if (amax > amin) {
    float s      = (amax - amin) * (1.0f / (float)K);
    float astart = fmaf((float)k, s, amin);
    float aend   = (k == K - 1) ? amax : fmaf((float)(k + 1), s, amin);

    TState S;
    S.acur = astart; S.aend = aend;
    int cx, cy, cz;
    axis_init(astart, aend, p0x, dsx, invx, S.stx, S.ix, S.alx, S.dax, cx);
    axis_init(astart, aend, p0y, dsy, invy, S.sty, S.iy, S.aly, S.day, cy);
    axis_init(astart, aend, p0z, dsz, invz, S.stz, S.iz, S.alz, S.daz, cz);

    int ns = cx + cy + cz + 3;          // +1 final partial, +2 cushion
    int nb = (ns + 3) >> 2;             // batches of 4
    if (nb < 2) nb = 2;                 // prologue needs two batches

    float difA[4], difB[4], difC[4];
    float vA[4], vB[4], vC[4];

#define ISSUE(X)   step4(image, S, dif##X, v##X)
#define CONSUME(X)                                                  \
    do { acc0 = fmaf(dif##X[0], v##X[0], acc0);                     \
         acc1 = fmaf(dif##X[1], v##X[1], acc1);                     \
         acc0 = fmaf(dif##X[2], v##X[2], acc0);                     \
         acc1 = fmaf(dif##X[3], v##X[3], acc1); } while (0)

    ISSUE(A);
    ISSUE(B);
    int produce = nb - 2;
    while (produce >= 3) {
      ISSUE(C); CONSUME(A);
      ISSUE(A); CONSUME(B);
      ISSUE(B); CONSUME(C);
      produce -= 3;
    }
    if (produce == 2) {
      ISSUE(C); CONSUME(A);
      ISSUE(A); CONSUME(B);
      CONSUME(C); CONSUME(A);
    } else if (produce == 1) {
      ISSUE(C); CONSUME(A);
      CONSUME(B); CONSUME(C);
    } else {
      CONSUME(A); CONSUME(B);
    }
#undef ISSUE
#undef CONSUME

    float rlen = sqrtf(dx * dx + dy * dy + dz * dz);
    acc0 = (acc0 + acc1) * rlen;
    acc1 = 0.0f;
  }

  float acc = acc0 + acc1;
  acc += __shfl_xor(acc, 1);
  acc += __shfl_xor(acc, 2);
  acc += __shfl_xor(acc, 4);
  acc += __shfl_xor(acc, 8);
  if (k == 0) out[ray] = acc;
}

extern "C" void kernel_launch(void* const* d_in, const int* in_sizes, int n_in,
                              void* d_out, int out_size, void* d_ws, size_t ws_size,
                              hipStream_t stream) {
  const float* image = (const float*)d_in[0];   // [128,128,128] f32
  const float* lors  = (const float*)d_in[1];   // [N,6] f32
  float* out = (float*)d_out;                   // [N] f32
  int n = out_size;

  // ws layout: hist[512] | offs[512] | keys[n] | perm[n]
  size_t need = ((size_t)2 * NBINS + 2 * (size_t)n) * sizeof(int);
  int* perm = nullptr;
  if (ws_size >= need) {
    int* hist = (int*)d_ws;
    int* offs = hist + NBINS;
    int* keys = offs + NBINS;
    perm      = keys + n;
    hipMemsetAsync(hist, 0, NBINS * sizeof(int), stream);
    int blocks = (n + 255) / 256;
    hipLaunchKernelGGL(ray_keys,     dim3(blocks), dim3(256), 0, stream, lors, n, keys, hist);
    hipLaunchKernelGGL(scan_bins,    dim3(1),      dim3(64),  0, stream, hist, offs);
    hipLaunchKernelGGL(scatter_perm, dim3(blocks), dim3(256), 0, stream, keys, offs, perm, n);
  }

  long total = (long)n * K;
  int block = 256;
  int grid = (int)((total + block - 1) / block);
  hipLaunchKernelGGL(siddon_fp, dim3(grid), dim3(block), 0, stream,
                     image, lors, out, perm, n);
}

// Round 8
// 56.183 us; speedup vs baseline: 9.4842x; 5.4938x over previous
//
#include <hip/hip_runtime.h>
#include <hip/hip_fp16.h>
#include <math.h>

// Siddon forward projection, 128^3 grid over [-1,1]^3, voxel = 1/64.
// K=16 lanes per LOR (alpha chunks), incremental traversal, depth-3 pipeline.
// Image is converted to fp16 in the workspace (4 MB -> resident in each XCD's
// 4 MiB L2), collapsing L2-miss latency/traffic for the scattered voxel loads.

static constexpr float VOX = 0.015625f;   // 2/128, exact power of two
static constexpr float INV_VOX = 64.0f;
static constexpr int   K = 16;
static constexpr int   LOGK = 4;
static constexpr int   NVOX = 128 * 128 * 128;

struct TState {
  float alx, aly, alz;   // next-crossing alpha per axis
  float dax, day, daz;   // alpha increment per crossing
  float acur, aend;
  int   ix, iy, iz;      // current voxel
  int   stx, sty, stz;   // walk direction
};

__device__ __forceinline__ void step4(const __half* __restrict__ image,
                                      TState& S, float dif4[4], float v4[4]) {
#pragma unroll
  for (int j = 0; j < 4; ++j) {
    float anext = fminf(fminf(S.alx, S.aly), S.alz);
    float astop = fminf(anext, S.aend);
    float diff  = astop - S.acur;
    unsigned orv = (unsigned)(S.ix | S.iy | S.iz);
    bool  use   = (diff > 0.0f) & (orv < 128u);
    int   idx   = (S.ix << 14) | (S.iy << 7) | S.iz;
    v4[j]  = __half2float(image[use ? idx : 0]);
    dif4[j] = use ? diff : 0.0f;
    S.acur = astop;
    bool cx = S.alx <= anext;
    bool cy = S.aly <= anext;
    bool cz = S.alz <= anext;
    S.ix += cx ? S.stx : 0;  S.alx += cx ? S.dax : 0.0f;
    S.iy += cy ? S.sty : 0;  S.aly += cy ? S.day : 0.0f;
    S.iz += cz ? S.stz : 0;  S.alz += cz ? S.daz : 0.0f;
  }
}

__device__ __forceinline__ void axis_init(float astart, float aend, float p0,
                                          float ds, float inv,
                                          int& st, int& iv, float& al, float& da,
                                          int& cnt) {
  float ts = (fmaf(astart, ds, p0) + 1.0f) * INV_VOX;
  float te = (fmaf(aend,   ds, p0) + 1.0f) * INV_VOX;
  int ip;
  if (ds > 0.0f) {
    ip = (int)floorf(ts) + 1;
    int il = (int)floorf(te); if (il > 128) il = 128;
    cnt = il - ip + 1; st = 1; iv = ip - 1;
  } else {
    ip = (int)ceilf(ts) - 1;
    int il = (int)ceilf(te); if (il < 0) il = 0;
    cnt = ip - il + 1; st = -1; iv = ip;
  }
  if (cnt < 0) cnt = 0;
  al = (fmaf((float)ip, VOX, -1.0f) - p0) * inv;
  da = VOX * fabsf(inv);
}

// --- image fp32 -> fp16 (workspace) -----------------------------------------
__global__ __launch_bounds__(256) void convert_h(
    const float* __restrict__ img, __half* __restrict__ h)
{
  int i = blockIdx.x * blockDim.x + threadIdx.x;
  int stride = gridDim.x * blockDim.x;
  for (; i < NVOX; i += stride) h[i] = __float2half(img[i]);
}

// --- traversal ---------------------------------------------------------------
__global__ __launch_bounds__(256) void siddon_fp(
    const __half* __restrict__ image,
    const float* __restrict__ lors,
    float* __restrict__ out, int n)
{
  int t    = blockIdx.x * blockDim.x + threadIdx.x;
  int ray  = t >> LOGK;
  int k    = t & (K - 1);
  if (ray >= n) return;

  const float* L = lors + (long)ray * 6;
  float p0x = L[0], p0y = L[1], p0z = L[2];
  float dx  = L[3] - p0x, dy = L[4] - p0y, dz = L[5] - p0z;

  const float eps = 1e-9f;
  float dsx = (fabsf(dx) < eps) ? eps : dx;
  float dsy = (fabsf(dy) < eps) ? eps : dy;
  float dsz = (fabsf(dz) < eps) ? eps : dz;

  float invx = __builtin_amdgcn_rcpf(dsx);
  float invy = __builtin_amdgcn_rcpf(dsy);
  float invz = __builtin_amdgcn_rcpf(dsz);

  float a0 = (-1.0f - p0x) * invx, a1 = (1.0f - p0x) * invx;
  float axmin = fminf(a0, a1), axmax = fmaxf(a0, a1);
  a0 = (-1.0f - p0y) * invy; a1 = (1.0f - p0y) * invy;
  float aymin = fminf(a0, a1), aymax = fmaxf(a0, a1);
  a0 = (-1.0f - p0z) * invz; a1 = (1.0f - p0z) * invz;
  float azmin = fminf(a0, a1), azmax = fmaxf(a0, a1);

  float amin = fmaxf(fmaxf(axmin, aymin), fmaxf(azmin, 0.0f));
  float amax = fminf(fminf(axmax, aymax), fminf(azmax, 1.0f));

  float acc0 = 0.0f, acc1 = 0.0f;
  if (amax > amin) {
    float s      = (amax - amin) * (1.0f / (float)K);
    float astart = fmaf((float)k, s, amin);
    float aend   = (k == K - 1) ? amax : fmaf((float)(k + 1), s, amin);

    TState S;
    S.acur = astart; S.aend = aend;
    int cx, cy, cz;
    axis_init(astart, aend, p0x, dsx, invx, S.stx, S.ix, S.alx, S.dax, cx);
    axis_init(astart, aend, p0y, dsy, invy, S.sty, S.iy, S.aly, S.day, cy);
    axis_init(astart, aend, p0z, dsz, invz, S.stz, S.iz, S.alz, S.daz, cz);

    int ns = cx + cy + cz + 3;          // +1 final partial, +2 cushion
    int nb = (ns + 3) >> 2;             // batches of 4
    if (nb < 2) nb = 2;                 // prologue needs two batches

    float difA[4], difB[4], difC[4];
    float vA[4], vB[4], vC[4];

#define ISSUE(X)   step4(image, S, dif##X, v##X)
#define CONSUME(X)                                                  \
    do { acc0 = fmaf(dif##X[0], v##X[0], acc0);                     \
         acc1 = fmaf(dif##X[1], v##X[1], acc1);                     \
         acc0 = fmaf(dif##X[2], v##X[2], acc0);                     \
         acc1 = fmaf(dif##X[3], v##X[3], acc1); } while (0)

    ISSUE(A);
    ISSUE(B);
    int produce = nb - 2;
    while (produce >= 3) {
      ISSUE(C); CONSUME(A);
      ISSUE(A); CONSUME(B);
      ISSUE(B); CONSUME(C);
      produce -= 3;
    }
    if (produce == 2) {
      ISSUE(C); CONSUME(A);
      ISSUE(A); CONSUME(B);
      CONSUME(C); CONSUME(A);
    } else if (produce == 1) {
      ISSUE(C); CONSUME(A);
      CONSUME(B); CONSUME(C);
    } else {
      CONSUME(A); CONSUME(B);
    }
#undef ISSUE
#undef CONSUME

    float rlen = sqrtf(dx * dx + dy * dy + dz * dz);
    acc0 = (acc0 + acc1) * rlen;
    acc1 = 0.0f;
  }

  float acc = acc0 + acc1;
  acc += __shfl_xor(acc, 1);
  acc += __shfl_xor(acc, 2);
  acc += __shfl_xor(acc, 4);
  acc += __shfl_xor(acc, 8);
  if (k == 0) out[ray] = acc;
}

extern "C" void kernel_launch(void* const* d_in, const int* in_sizes, int n_in,
                              void* d_out, int out_size, void* d_ws, size_t ws_size,
                              hipStream_t stream) {
  const float* image = (const float*)d_in[0];   // [128,128,128] f32
  const float* lors  = (const float*)d_in[1];   // [N,6] f32
  float* out = (float*)d_out;                   // [N] f32
  int n = out_size;

  __half* h = (__half*)d_ws;                    // 4 MB fp16 image
  hipLaunchKernelGGL(convert_h, dim3(2048), dim3(256), 0, stream, image, h);

  long total = (long)n * K;
  int block = 256;
  int grid = (int)((total + block - 1) / block);
  hipLaunchKernelGGL(siddon_fp, dim3(grid), dim3(block), 0, stream,
                     h, lors, out, n);
}